// Round 6
// baseline (826.157 us; speedup 1.0000x reference)
//
#include <hip/hip_runtime.h>
#include <hip/hip_bf16.h>
#include <stdint.h>

typedef __attribute__((ext_vector_type(8))) __bf16 bf16x8;
typedef __attribute__((ext_vector_type(4))) float f32x4;

#define MFMA16(a, b, c) __builtin_amdgcn_mfma_f32_16x16x32_bf16(a, b, c, 0, 0, 0)

__device__ __forceinline__ void gload16(const void* g, void* l) {
  __builtin_amdgcn_global_load_lds((const __attribute__((address_space(1))) void*)g,
                                   (__attribute__((address_space(3))) void*)l, 16, 0, 0);
}

// ---------------------------------------------------------------------------
// prep+cvt fused: blocks [0,16384): q fp32 -> bf16 (8 elems/thread)
//                 blocks [16384,20742): weight fold/transpose + bias_frag
// ---------------------------------------------------------------------------
__global__ __launch_bounds__(256) void prep_cvt_kernel(
    const float* __restrict__ qin, __bf16* __restrict__ qbf,
    const float* __restrict__ wq, const float* __restrict__ bq,
    const float* __restrict__ wkv, const float* __restrict__ bkv,
    const float* __restrict__ wproj, const float* __restrict__ btab,
    const int* __restrict__ relidx,
    __bf16* __restrict__ W1t, __bf16* __restrict__ WpT,
    float* __restrict__ bias1, float* __restrict__ bias_frag) {
  if (blockIdx.x < 16384) {
    int t = blockIdx.x * 256 + threadIdx.x;
    const float4* p = (const float4*)qin + (size_t)t * 2;
    float4 a = p[0], b = p[1];
    bf16x8 v = {(__bf16)a.x, (__bf16)a.y, (__bf16)a.z, (__bf16)a.w,
                (__bf16)b.x, (__bf16)b.y, (__bf16)b.z, (__bf16)b.w};
    *((bf16x8*)qbf + t) = v;
    return;
  }
  const float scale = 0.17677669529663687f;  // 32^-0.5
  int t = (blockIdx.x - 16384) * 256 + threadIdx.x;
  if (t < 786432) {
    int j = t >> 9, kk = t & 511;
    float v = (j < 512) ? wq[kk * 512 + j] * scale : wkv[kk * 1024 + (j - 512)];
    W1t[t] = (__bf16)v;
  } else if (t < 1048576) {
    int u = t - 786432;
    int j = u >> 9, kk = u & 511;
    WpT[u] = (__bf16)wproj[kk * 512 + j];
  } else if (t < 1050112) {
    int j = t - 1048576;
    bias1[j] = (j < 512) ? bq[j] * scale : bkv[j - 512];
  } else if (t < 1115648) {
    int u = t - 1050112;
    int r = u & 3, l = (u >> 2) & 63, nj = (u >> 8) & 3, mi = (u >> 10) & 3, h = u >> 12;
    int qq = mi * 16 + (l >> 4) * 4 + r;
    int nn = nj * 16 + (l & 15);
    bias_frag[u] = btab[relidx[qq * 64 + nn] * 16 + h];
  }
}

// ---------------------------------------------------------------------------
// GEMM1: qbf[65536,512] x W1t -> qh, kb, vv   all [bh][n][d] row-major
// 128x128 tile, BK=32, 4 waves (2x2). XCD-chunked block swizzle (T1).
// ---------------------------------------------------------------------------
__global__ __launch_bounds__(256) void gemm1_kernel(
    const __bf16* __restrict__ A, const __bf16* __restrict__ W1t,
    const float* __restrict__ bias1,
    __bf16* __restrict__ qh, __bf16* __restrict__ kb, __bf16* __restrict__ vv) {
  __shared__ __bf16 As[128 * 32];  // [row][k]
  __shared__ __bf16 Bs[128 * 32];  // [col n][k]
  int tid = threadIdx.x;
  int w = tid >> 6, l = tid & 63, c = l & 15, g = l >> 4;
  int wm = w >> 1, wn = w & 1;
  // XCD swizzle: nwg=6144, 8 XCDs, 768 blocks/XCD chunk. bijective.
  int bflat = (blockIdx.x & 7) * 768 + (blockIdx.x >> 3);
  int bx = bflat % 12, by = bflat / 12;
  int r0 = by * 128, n0 = bx * 128;

  f32x4 acc[4][4] = {};
  int e0 = w * 1024 + l * 8;
  int rn0 = e0 >> 5, rk0 = e0 & 31;
  int e1 = e0 + 512;
  int rn1 = e1 >> 5, rk1 = e1 & 31;

  for (int kt = 0; kt < 16; ++kt) {
    int k0 = kt * 32;
    __syncthreads();
    gload16(A + (size_t)(r0 + rn0) * 512 + k0 + rk0, (void*)(As + w * 1024));
    gload16(A + (size_t)(r0 + rn1) * 512 + k0 + rk1, (void*)(As + w * 1024 + 512));
    gload16(W1t + (size_t)(n0 + rn0) * 512 + k0 + rk0, (void*)(Bs + w * 1024));
    gload16(W1t + (size_t)(n0 + rn1) * 512 + k0 + rk1, (void*)(Bs + w * 1024 + 512));
    __syncthreads();
    bf16x8 af[4], bfr[4];
#pragma unroll
    for (int mi = 0; mi < 4; mi++) af[mi] = *(const bf16x8*)(As + (wm * 64 + mi * 16 + c) * 32 + g * 8);
#pragma unroll
    for (int nj = 0; nj < 4; nj++) bfr[nj] = *(const bf16x8*)(Bs + (wn * 64 + nj * 16 + c) * 32 + g * 8);
#pragma unroll
    for (int mi = 0; mi < 4; mi++)
#pragma unroll
      for (int nj = 0; nj < 4; nj++)
        acc[mi][nj] = MFMA16(af[mi], bfr[nj], acc[mi][nj]);
  }

  __bf16* dst = (bx < 4) ? qh : (bx < 8) ? kb : vv;  // block-uniform

  float bia[4];
#pragma unroll
  for (int nj = 0; nj < 4; nj++) bia[nj] = bias1[n0 + wn * 64 + nj * 16 + c];
  int rowbase = r0 + wm * 64 + g * 4;
  int colbase = n0 + wn * 64 + c;
#pragma unroll
  for (int mi = 0; mi < 4; mi++) {
#pragma unroll
    for (int nj = 0; nj < 4; nj++) {
      int col = colbase + nj * 16;
      int jj = col & 511;  // region base is 512-aligned
      int h = jj >> 5, d = jj & 31;
#pragma unroll
      for (int r = 0; r < 4; r++) {
        int row = rowbase + mi * 16 + r;
        int b = row >> 6, tok = row & 63;
        float val = acc[mi][nj][r] + bia[nj];
        dst[(size_t)(b * 16 + h) * 2048 + tok * 32 + d] = (__bf16)val;
      }
    }
  }
}

// ---------------------------------------------------------------------------
// Fused attention + out-proj. Block = half window (32 q-tokens), 8 waves.
// Wave w handles heads 2w, 2w+1: S=qh@k^T + bias, softmax (attn out f32),
// PV (V B-frags read from global), xin staged in LDS (XOR-swizzled),
// then out-proj 32x512 @ WpT^T + bproj -> x.  ONE __syncthreads total.
// ---------------------------------------------------------------------------
__global__ __launch_bounds__(512) void attn_proj_kernel(
    const __bf16* __restrict__ qh, const __bf16* __restrict__ kb,
    const __bf16* __restrict__ vv, const float* __restrict__ bias_frag,
    const __bf16* __restrict__ WpT, const float* __restrict__ bproj,
    float* __restrict__ attn_out, float* __restrict__ x_out) {
  __shared__ __align__(16) __bf16 Pb[8][16 * 76];   // per-wave P chunk, stride 76 (anti-conflict)
  __shared__ __align__(16) char xinb[32 * 1024];    // xin[32][512] bf16, byte ^= (row&7)<<4
  int bid = blockIdx.x;
  int b = bid >> 1, half = bid & 1, tok0 = half * 32;
  int tid = threadIdx.x;
  int w = tid >> 6, l = tid & 63, c = l & 15, g = l >> 4;
  __bf16* pb = &Pb[w][0];

#pragma unroll
  for (int hi = 0; hi < 2; ++hi) {
    int h = w * 2 + hi;
    int bh = b * 16 + h;
    const __bf16* qp = qh + (size_t)bh * 2048;
    const __bf16* kp = kb + (size_t)bh * 2048;
    const __bf16* vp = vv + (size_t)bh * 2048;

    // independent global loads issued up front; latency hides under QK^T
    bf16x8 bv[2][2];  // bv[dj][kk][e] = V[32kk+8g+e][16dj+c]
#pragma unroll
    for (int dj = 0; dj < 2; dj++)
#pragma unroll
      for (int kk = 0; kk < 2; kk++)
#pragma unroll
        for (int e = 0; e < 8; e++)
          bv[dj][kk][e] = vp[(32 * kk + 8 * g + e) * 32 + 16 * dj + c];

    bf16x8 af[2], bfr[4];
#pragma unroll
    for (int mi = 0; mi < 2; mi++) af[mi] = *(const bf16x8*)(qp + (tok0 + mi * 16 + c) * 32 + g * 8);
#pragma unroll
    for (int nj = 0; nj < 4; nj++) bfr[nj] = *(const bf16x8*)(kp + (nj * 16 + c) * 32 + g * 8);

    f32x4 acc[2][4];
#pragma unroll
    for (int mi = 0; mi < 2; mi++)
#pragma unroll
      for (int nj = 0; nj < 4; nj++)
        acc[mi][nj] = *(const f32x4*)(bias_frag +
            ((size_t)((h * 4 + half * 2 + mi) * 4 + nj) * 64 + l) * 4);
#pragma unroll
    for (int mi = 0; mi < 2; mi++)
#pragma unroll
      for (int nj = 0; nj < 4; nj++)
        acc[mi][nj] = MFMA16(af[mi], bfr[nj], acc[mi][nj]);

    float* ao = attn_out + (size_t)bh * 4096;
    f32x4 xacc[2][2] = {};
#pragma unroll
    for (int mi = 0; mi < 2; mi++) {
#pragma unroll
      for (int r = 0; r < 4; r++) {
        float m = fmaxf(fmaxf(acc[mi][0][r], acc[mi][1][r]), fmaxf(acc[mi][2][r], acc[mi][3][r]));
        m = fmaxf(m, __shfl_xor(m, 1));
        m = fmaxf(m, __shfl_xor(m, 2));
        m = fmaxf(m, __shfl_xor(m, 4));
        m = fmaxf(m, __shfl_xor(m, 8));
        float p0 = __expf(acc[mi][0][r] - m);
        float p1 = __expf(acc[mi][1][r] - m);
        float p2 = __expf(acc[mi][2][r] - m);
        float p3 = __expf(acc[mi][3][r] - m);
        float s = p0 + p1 + p2 + p3;
        s += __shfl_xor(s, 1);
        s += __shfl_xor(s, 2);
        s += __shfl_xor(s, 4);
        s += __shfl_xor(s, 8);
        float rs = 1.0f / s;
        p0 *= rs; p1 *= rs; p2 *= rs; p3 *= rs;
        int rl = g * 4 + r;                 // row within this 16-row chunk
        int rowg = tok0 + mi * 16 + rl;     // global q-token in window
        ao[rowg * 64 + c] = p0;
        ao[rowg * 64 + 16 + c] = p1;
        ao[rowg * 64 + 32 + c] = p2;
        ao[rowg * 64 + 48 + c] = p3;
        pb[rl * 76 + c] = (__bf16)p0;
        pb[rl * 76 + 16 + c] = (__bf16)p1;
        pb[rl * 76 + 32 + c] = (__bf16)p2;
        pb[rl * 76 + 48 + c] = (__bf16)p3;
      }
      // PV for this 16-row chunk (wave-private LDS; compiler orders via lgkmcnt)
      bf16x8 pa[2];
#pragma unroll
      for (int kk = 0; kk < 2; kk++)
        pa[kk] = *(const bf16x8*)(pb + c * 76 + kk * 32 + g * 8);
#pragma unroll
      for (int dj = 0; dj < 2; dj++)
#pragma unroll
        for (int kk = 0; kk < 2; kk++)
          xacc[mi][dj] = MFMA16(pa[kk], bv[dj][kk], xacc[mi][dj]);
    }

    // xin[row][col] = x_in (heads concatenated), swizzled byte ^= (row&7)<<4
#pragma unroll
    for (int mi = 0; mi < 2; mi++)
#pragma unroll
      for (int dj = 0; dj < 2; dj++)
#pragma unroll
        for (int r = 0; r < 4; r++) {
          int row = mi * 16 + g * 4 + r;
          int col = h * 32 + dj * 16 + c;
          int byte = (row * 1024 + col * 2) ^ ((row & 7) << 4);
          *(__bf16*)(xinb + byte) = (__bf16)xacc[mi][dj][r];
        }
  }
  __syncthreads();

  // ---- out-proj: rows tok0..tok0+32, wave w -> cols w*64..w*64+64 ----
  int n0 = w * 64;
  f32x4 acc2[2][4] = {};
  for (int kt = 0; kt < 16; ++kt) {
    bf16x8 af2[2], bfr2[4];
#pragma unroll
    for (int mi = 0; mi < 2; mi++) {
      int row = mi * 16 + c;
      int byte = (row * 1024 + kt * 64 + g * 16) ^ ((row & 7) << 4);
      af2[mi] = *(const bf16x8*)(xinb + byte);
    }
#pragma unroll
    for (int nj = 0; nj < 4; nj++)
      bfr2[nj] = *(const bf16x8*)(WpT + (size_t)(n0 + nj * 16 + c) * 512 + kt * 32 + g * 8);
#pragma unroll
    for (int mi = 0; mi < 2; mi++)
#pragma unroll
      for (int nj = 0; nj < 4; nj++)
        acc2[mi][nj] = MFMA16(af2[mi], bfr2[nj], acc2[mi][nj]);
  }
  float bia[4];
#pragma unroll
  for (int nj = 0; nj < 4; nj++) bia[nj] = bproj[n0 + nj * 16 + c];
#pragma unroll
  for (int mi = 0; mi < 2; mi++)
#pragma unroll
    for (int nj = 0; nj < 4; nj++)
#pragma unroll
      for (int r = 0; r < 4; r++) {
        int row = b * 64 + tok0 + mi * 16 + g * 4 + r;
        x_out[(size_t)row * 512 + n0 + nj * 16 + c] = acc2[mi][nj][r] + bia[nj];
      }
}

// ---------------------------------------------------------------------------
extern "C" void kernel_launch(void* const* d_in, const int* in_sizes, int n_in,
                              void* d_out, int out_size, void* d_ws, size_t ws_size,
                              hipStream_t stream) {
  const float* q = (const float*)d_in[0];
  const float* wq = (const float*)d_in[1];
  const float* bq = (const float*)d_in[2];
  const float* wkv = (const float*)d_in[3];
  const float* bkv = (const float*)d_in[4];
  const float* wproj = (const float*)d_in[5];
  const float* bproj = (const float*)d_in[6];
  const float* btab = (const float*)d_in[7];
  const int* relidx = (const int*)d_in[8];

  float* x_out = (float*)d_out;
  float* attn_out = x_out + 33554432;
  // qbf lives in the attn region of d_out: dead until attn_proj overwrites it,
  // and gemm1 (its only reader) completes before attn_proj launches.
  __bf16* qbf = (__bf16*)attn_out;

  char* ws = (char*)d_ws;
  __bf16* qh = (__bf16*)(ws);                  // 67,108,864 B
  __bf16* kb = (__bf16*)(ws + 67108864);       // 67,108,864 B
  __bf16* vv = (__bf16*)(ws + 134217728);      // 67,108,864 B
  __bf16* W1t = (__bf16*)(ws + 201326592);     //  1,572,864 B
  __bf16* WpT = (__bf16*)(ws + 202899456);     //    524,288 B
  float* bias1 = (float*)(ws + 203423744);     //      6,144 B
  float* bfrag = (float*)(ws + 203429888);     //    262,144 B  (end: 203,692,032)

  hipLaunchKernelGGL(prep_cvt_kernel, dim3(20742), dim3(256), 0, stream,
                     q, qbf, wq, bq, wkv, bkv, wproj, btab, relidx, W1t, WpT, bias1, bfrag);
  hipLaunchKernelGGL(gemm1_kernel, dim3(6144), dim3(256), 0, stream,
                     qbf, W1t, bias1, qh, kb, vv);
  hipLaunchKernelGGL(attn_proj_kernel, dim3(2048), dim3(512), 0, stream,
                     qh, kb, vv, bfrag, WpT, bproj, attn_out, x_out);
}